// Round 1
// baseline (468.840 us; speedup 1.0000x reference)
//
#include <hip/hip_runtime.h>

#define IN_DIM 128
#define OUT_DIM 128
#define KERN 3
#define NCOL 384          // KERN * OUT_DIM
#define BN_EPS 1e-5f
#define SLOPE 0.01f

// ---------------------------------------------------------------------------
// GEMM: proj[M,384] = h[M,128] @ fc_w[128,384]   (f32 vector FMA; no f32 MFMA)
// Block: 256 threads, tile 64(M) x 128(N), K staged in chunks of 32.
// Each thread computes a 4x8 micro-tile.
// ---------------------------------------------------------------------------
#define TM 64
#define TN 128
#define TK 32

__global__ __launch_bounds__(256) void gemm_proj(
    const float* __restrict__ A, const float* __restrict__ B,
    float* __restrict__ C, int M)
{
    __shared__ float As[TK][TM + 4];   // A tile transposed: As[k][m], padded (272B rows, 16B aligned)
    __shared__ float Bs[TK][TN];       // B tile row-major: Bs[k][n]

    const int m0 = blockIdx.x * TM;
    const int n0 = blockIdx.y * TN;
    const int tid = threadIdx.x;
    const int tr = tid >> 4;           // 0..15 -> rows tr*4..tr*4+3
    const int tc = tid & 15;           // 0..15 -> cols tc*8..tc*8+7

    float acc[4][8];
    #pragma unroll
    for (int i = 0; i < 4; ++i)
        #pragma unroll
        for (int j = 0; j < 8; ++j) acc[i][j] = 0.f;

    for (int k0 = 0; k0 < IN_DIM; k0 += TK) {
        // --- load A tile (64 rows x 32 k), write transposed into LDS
        {
            const int kk4 = (tid & 7) * 4;
            #pragma unroll
            for (int p = 0; p < 2; ++p) {
                const int r = (tid >> 3) + p * 32;
                const int row = m0 + r;
                float4 v = make_float4(0.f, 0.f, 0.f, 0.f);
                if (row < M)
                    v = *(const float4*)&A[(size_t)row * IN_DIM + k0 + kk4];
                As[kk4 + 0][r] = v.x;
                As[kk4 + 1][r] = v.y;
                As[kk4 + 2][r] = v.z;
                As[kk4 + 3][r] = v.w;
            }
        }
        // --- load B tile (32 k x 128 n)
        {
            const int c4 = (tid & 31) * 4;
            const int kb = tid >> 5;
            #pragma unroll
            for (int p = 0; p < 4; ++p) {
                const int kk = kb + p * 8;
                *(float4*)&Bs[kk][c4] =
                    *(const float4*)&B[(size_t)(k0 + kk) * NCOL + n0 + c4];
            }
        }
        __syncthreads();

        #pragma unroll
        for (int kk = 0; kk < TK; ++kk) {
            const float4 a  = *(const float4*)&As[kk][tr * 4];
            const float4 b0 = *(const float4*)&Bs[kk][tc * 8];
            const float4 b1 = *(const float4*)&Bs[kk][tc * 8 + 4];
            const float av[4] = {a.x, a.y, a.z, a.w};
            const float bv[8] = {b0.x, b0.y, b0.z, b0.w, b1.x, b1.y, b1.z, b1.w};
            #pragma unroll
            for (int i = 0; i < 4; ++i)
                #pragma unroll
                for (int j = 0; j < 8; ++j)
                    acc[i][j] += av[i] * bv[j];
        }
        __syncthreads();
    }

    #pragma unroll
    for (int i = 0; i < 4; ++i) {
        const int row = m0 + tr * 4 + i;
        if (row < M) {
            float4 v0 = make_float4(acc[i][0], acc[i][1], acc[i][2], acc[i][3]);
            float4 v1 = make_float4(acc[i][4], acc[i][5], acc[i][6], acc[i][7]);
            *(float4*)&C[(size_t)row * NCOL + n0 + tc * 8]     = v0;
            *(float4*)&C[(size_t)row * NCOL + n0 + tc * 8 + 4] = v1;
        }
    }
}

// ---------------------------------------------------------------------------
// Edge stage: msg[e,o] = sum_k gauss[e,k] * proj[src[e], k*128+o];
// atomic scatter-add into agg[dst[e], o].  128 threads per edge (one per o).
// ---------------------------------------------------------------------------
__global__ __launch_bounds__(256) void edge_scatter(
    const float* __restrict__ pseudo, const int* __restrict__ src,
    const int* __restrict__ dst, const float* __restrict__ proj,
    const float* __restrict__ mu, const float* __restrict__ isg,
    float* __restrict__ agg, int E)
{
    const int e = blockIdx.x * 2 + (threadIdx.x >> 7);
    const int o = threadIdx.x & 127;
    if (e >= E) return;

    const float2 p = *(const float2*)&pseudo[(size_t)e * 2];
    float w[KERN];
    #pragma unroll
    for (int k = 0; k < KERN; ++k) {
        const float dx = (p.x - mu[2 * k])     * isg[2 * k];
        const float dy = (p.y - mu[2 * k + 1]) * isg[2 * k + 1];
        w[k] = __expf(-0.5f * (dx * dx + dy * dy));
    }
    const int s = src[e];
    const int d = dst[e];
    const float* pr = proj + (size_t)s * NCOL + o;
    const float m = w[0] * pr[0] + w[1] * pr[OUT_DIM] + w[2] * pr[2 * OUT_DIM];
    atomicAdd(&agg[(size_t)d * OUT_DIM + o], m);
}

// ---------------------------------------------------------------------------
// Zero-fill helper (avoid relying on memset semantics under graph capture)
// ---------------------------------------------------------------------------
__global__ void zero_f32(float* __restrict__ p, int n)
{
    const int i = blockIdx.x * 256 + threadIdx.x;
    if (i < n) p[i] = 0.f;
}

// ---------------------------------------------------------------------------
// BN stats: per-channel sum & sumsq over N rows -> stats[0..127]=sum,
// stats[128..255]=sumsq
// ---------------------------------------------------------------------------
__global__ __launch_bounds__(256) void bn_stats(
    const float* __restrict__ agg, float* __restrict__ stats, int N)
{
    const int tid = threadIdx.x;
    const int o = tid & 127;
    const int half = tid >> 7;
    float s = 0.f, ss = 0.f;
    for (int r = blockIdx.x * 2 + half; r < N; r += gridDim.x * 2) {
        const float v = agg[(size_t)r * OUT_DIM + o];
        s += v;
        ss += v * v;
    }
    __shared__ float rs[256], rss[256];
    rs[tid] = s;
    rss[tid] = ss;
    __syncthreads();
    if (tid < 128) {
        atomicAdd(&stats[tid],       rs[tid] + rs[tid + 128]);
        atomicAdd(&stats[128 + tid], rss[tid] + rss[tid + 128]);
    }
}

// ---------------------------------------------------------------------------
// Finalize: BN normalize (bias cancels exactly), leaky_relu, + residual h.
// In-place on d_out (which holds agg).  float4-vectorized.
// ---------------------------------------------------------------------------
__global__ __launch_bounds__(256) void finalize(
    float* __restrict__ out, const float* __restrict__ h,
    const float* __restrict__ stats, const float* __restrict__ gamma,
    const float* __restrict__ beta, int total4, float invN)
{
    const int idx = blockIdx.x * 256 + threadIdx.x;
    if (idx >= total4) return;
    const int i4 = idx * 4;
    const int o4 = i4 & 127;

    float4 a  = *(const float4*)&out[i4];
    const float4 hh = *(const float4*)&h[i4];
    float r[4] = {a.x, a.y, a.z, a.w};
    const float hv[4] = {hh.x, hh.y, hh.z, hh.w};
    float res[4];
    #pragma unroll
    for (int j = 0; j < 4; ++j) {
        const int o = o4 + j;
        const float mean = stats[o] * invN;
        const float var = stats[128 + o] * invN - mean * mean;
        float x = (r[j] - mean) * rsqrtf(var + BN_EPS) * gamma[o] + beta[o];
        x = x > 0.f ? x : SLOPE * x;
        res[j] = x + hv[j];
    }
    *(float4*)&out[i4] = make_float4(res[0], res[1], res[2], res[3]);
}

// ---------------------------------------------------------------------------
extern "C" void kernel_launch(void* const* d_in, const int* in_sizes, int n_in,
                              void* d_out, int out_size, void* d_ws, size_t ws_size,
                              hipStream_t stream)
{
    const float* h      = (const float*)d_in[0];
    const float* pseudo = (const float*)d_in[1];
    const int*   src    = (const int*)d_in[2];
    const int*   dst    = (const int*)d_in[3];
    const float* fc_w   = (const float*)d_in[4];
    const float* mu     = (const float*)d_in[5];
    const float* isg    = (const float*)d_in[6];
    // d_in[7] = bias: cancels exactly inside BatchNorm -> unused
    const float* gamma  = (const float*)d_in[8];
    const float* beta   = (const float*)d_in[9];

    const int N = in_sizes[0] / IN_DIM;   // 50000
    const int E = in_sizes[2];            // 800000

    float* proj  = (float*)d_ws;                                   // N*384 f32 = 76.8 MB
    float* stats = (float*)((char*)d_ws + (size_t)N * NCOL * 4);   // 256 f32
    float* agg   = (float*)d_out;                                  // accumulate in d_out

    const int total = N * OUT_DIM;

    // zero accumulator + stats
    zero_f32<<<(total + 255) / 256, 256, 0, stream>>>(agg, total);
    zero_f32<<<1, 256, 0, stream>>>(stats, 256);

    // 1. proj = h @ fc_w
    dim3 g1((N + TM - 1) / TM, NCOL / TN);
    gemm_proj<<<g1, 256, 0, stream>>>(h, fc_w, proj, N);

    // 2. edge gather/scatter
    edge_scatter<<<(E + 1) / 2, 256, 0, stream>>>(pseudo, src, dst, proj, mu,
                                                  isg, agg, E);

    // 3. BN statistics
    bn_stats<<<512, 256, 0, stream>>>(agg, stats, N);

    // 4. BN + leaky_relu + residual
    finalize<<<(total / 4 + 255) / 256, 256, 0, stream>>>(
        agg, h, stats, gamma, beta, total / 4, 1.0f / (float)N);
}

// Round 2
// 308.902 us; speedup vs baseline: 1.5178x; 1.5178x over previous
//
#include <hip/hip_runtime.h>

#define IN_DIM 128
#define OUT_DIM 128
#define KERN 3
#define NCOL 384          // KERN * IN_DIM (g row) ; also KERN*OUT_DIM
#define BN_EPS 1e-5f
#define SLOPE 0.01f

typedef unsigned int uint;
typedef unsigned short ushort;

__device__ __forceinline__ ushort f32_to_bf16(float f) {
    uint b = __float_as_uint(f);
    return (ushort)((b + 0x7fffu + ((b >> 16) & 1u)) >> 16);
}
__device__ __forceinline__ float bf16_to_f32(ushort u) {
    return __uint_as_float(((uint)u) << 16);
}

// ---------------------------------------------------------------------------
// zero helper
// ---------------------------------------------------------------------------
__global__ void zero_i32(int* __restrict__ p, int n)
{
    const int i = blockIdx.x * 256 + threadIdx.x;
    if (i < n) p[i] = 0;
}

// ---------------------------------------------------------------------------
// 1. histogram of dst
// ---------------------------------------------------------------------------
__global__ __launch_bounds__(256) void hist_dst(
    const int* __restrict__ dst, int* __restrict__ counts, int E)
{
    const int e = blockIdx.x * 256 + threadIdx.x;
    if (e < E) atomicAdd(&counts[dst[e]], 1);
}

// ---------------------------------------------------------------------------
// 2. prefix sum of counts -> row_start  (3 small kernels)
// ---------------------------------------------------------------------------
#define SCHUNK 512

__global__ __launch_bounds__(256) void scan1(
    const int* __restrict__ counts, int* __restrict__ blocksum, int N)
{
    __shared__ int s[256];
    const int tid = threadIdx.x;
    const int base = blockIdx.x * SCHUNK;
    int v = 0;
    if (base + tid < N) v += counts[base + tid];
    if (base + 256 + tid < N) v += counts[base + 256 + tid];
    s[tid] = v;
    __syncthreads();
    for (int off = 128; off > 0; off >>= 1) {
        if (tid < off) s[tid] += s[tid + off];
        __syncthreads();
    }
    if (tid == 0) blocksum[blockIdx.x] = s[0];
}

__global__ void scan2(const int* __restrict__ blocksum,
                      int* __restrict__ chunk_off,
                      int* __restrict__ row_start, int nch, int N, int E)
{
    if (threadIdx.x == 0) {
        int run = 0;
        for (int b = 0; b < nch; ++b) { chunk_off[b] = run; run += blocksum[b]; }
        row_start[N] = E;
    }
}

__global__ __launch_bounds__(512) void scan3(
    const int* __restrict__ counts, const int* __restrict__ chunk_off,
    int* __restrict__ row_start, int N)
{
    __shared__ int s[SCHUNK];
    const int tid = threadIdx.x;
    const int i = blockIdx.x * SCHUNK + tid;
    const int v0 = (i < N) ? counts[i] : 0;
    s[tid] = v0;
    __syncthreads();
    for (int off = 1; off < SCHUNK; off <<= 1) {
        int t = 0;
        if (tid >= off) t = s[tid - off];
        __syncthreads();
        s[tid] += t;
        __syncthreads();
    }
    if (i < N) row_start[i] = chunk_off[blockIdx.x] + s[tid] - v0;
}

// ---------------------------------------------------------------------------
// 3. per-edge: gaussian weights + scatter {w0,w1,w2,src} into dst-sorted slot
// ---------------------------------------------------------------------------
__global__ __launch_bounds__(256) void edge_prep(
    const float* __restrict__ pseudo, const int* __restrict__ src,
    const int* __restrict__ dst, const float* __restrict__ mu,
    const float* __restrict__ isg, const int* __restrict__ row_start,
    int* __restrict__ cursor, float4* __restrict__ edata, int E)
{
    const int e = blockIdx.x * 256 + threadIdx.x;
    if (e >= E) return;
    const float2 p = *(const float2*)&pseudo[(size_t)e * 2];
    float w[KERN];
    #pragma unroll
    for (int k = 0; k < KERN; ++k) {
        const float dx = (p.x - mu[2 * k])     * isg[2 * k];
        const float dy = (p.y - mu[2 * k + 1]) * isg[2 * k + 1];
        w[k] = __expf(-0.5f * (dx * dx + dy * dy));
    }
    const int d = dst[e];
    const int pos = row_start[d] + atomicAdd(&cursor[d], 1);
    edata[pos] = make_float4(w[0], w[1], w[2], __int_as_float(src[e]));
}

// ---------------------------------------------------------------------------
// 4. aggregation: g[d,k,i] = sum_{e->d} w_ek * h[src_e, i]   (bf16 out)
//    one node per 128 threads (2 nodes per 256-block); no atomics.
// ---------------------------------------------------------------------------
__global__ __launch_bounds__(256) void edge_aggregate(
    const float* __restrict__ h, const float4* __restrict__ edata,
    const int* __restrict__ row_start, ushort* __restrict__ g, int N)
{
    const int d = blockIdx.x * 2 + (threadIdx.x >> 7);
    const int o = threadIdx.x & 127;
    if (d >= N) return;

    const int beg = row_start[d];
    const int end = row_start[d + 1];
    float a0 = 0.f, a1 = 0.f, a2 = 0.f;

    int i = beg;
    for (; i + 1 < end; i += 2) {
        const float4 e0 = edata[i];
        const float4 e1 = edata[i + 1];
        const float v0 = h[(size_t)__float_as_int(e0.w) * IN_DIM + o];
        const float v1 = h[(size_t)__float_as_int(e1.w) * IN_DIM + o];
        a0 += e0.x * v0; a1 += e0.y * v0; a2 += e0.z * v0;
        a0 += e1.x * v1; a1 += e1.y * v1; a2 += e1.z * v1;
    }
    if (i < end) {
        const float4 e0 = edata[i];
        const float v0 = h[(size_t)__float_as_int(e0.w) * IN_DIM + o];
        a0 += e0.x * v0; a1 += e0.y * v0; a2 += e0.z * v0;
    }

    ushort* gp = g + (size_t)d * NCOL + o;
    gp[0]           = f32_to_bf16(a0);
    gp[IN_DIM]      = f32_to_bf16(a1);
    gp[2 * IN_DIM]  = f32_to_bf16(a2);
}

// ---------------------------------------------------------------------------
// 5. GEMM: agg[M,128] = g[M,384](bf16) @ B,  B[c,o] = fc_w[(c&127)*384 + (c>>7)*128 + o]
//    Block 256 thr, tile 64(M) x 128(N=all), K chunks of 32, 4x8 micro-tile.
// ---------------------------------------------------------------------------
#define TM 64
#define TN 128
#define TK 32

__global__ __launch_bounds__(256) void gemm_agg(
    const ushort* __restrict__ A, const float* __restrict__ W,
    float* __restrict__ C, int M)
{
    __shared__ float As[TK][TM + 4];
    __shared__ float Bs[TK][TN];

    const int m0 = blockIdx.x * TM;
    const int tid = threadIdx.x;
    const int tr = tid >> 4;
    const int tc = tid & 15;

    float acc[4][8];
    #pragma unroll
    for (int i = 0; i < 4; ++i)
        #pragma unroll
        for (int j = 0; j < 8; ++j) acc[i][j] = 0.f;

    for (int k0 = 0; k0 < NCOL; k0 += TK) {
        // A tile: 64 rows x 32 k of bf16; each thread loads 8 bf16 (16B)
        {
            const int m  = tid >> 2;
            const int k8 = (tid & 3) * 8;
            const int row = m0 + m;
            uint4 v = make_uint4(0, 0, 0, 0);
            if (row < M)
                v = *(const uint4*)&A[(size_t)row * NCOL + k0 + k8];
            const uint u[4] = {v.x, v.y, v.z, v.w};
            #pragma unroll
            for (int q = 0; q < 4; ++q) {
                As[k8 + 2 * q][m]     = __uint_as_float(u[q] << 16);
                As[k8 + 2 * q + 1][m] = __uint_as_float(u[q] & 0xffff0000u);
            }
        }
        // B tile with (k,i) permutation of fc_w
        {
            const int c4 = (tid & 31) * 4;
            const int kb = tid >> 5;
            #pragma unroll
            for (int p = 0; p < 4; ++p) {
                const int kk = kb + p * 8;
                const int c = k0 + kk;
                const float* bp = W + (size_t)(c & 127) * NCOL + ((c >> 7) << 7);
                *(float4*)&Bs[kk][c4] = *(const float4*)&bp[c4];
            }
        }
        __syncthreads();

        #pragma unroll
        for (int kk = 0; kk < TK; ++kk) {
            const float4 a  = *(const float4*)&As[kk][tr * 4];
            const float4 b0 = *(const float4*)&Bs[kk][tc * 8];
            const float4 b1 = *(const float4*)&Bs[kk][tc * 8 + 4];
            const float av[4] = {a.x, a.y, a.z, a.w};
            const float bv[8] = {b0.x, b0.y, b0.z, b0.w, b1.x, b1.y, b1.z, b1.w};
            #pragma unroll
            for (int i = 0; i < 4; ++i)
                #pragma unroll
                for (int j = 0; j < 8; ++j)
                    acc[i][j] += av[i] * bv[j];
        }
        __syncthreads();
    }

    #pragma unroll
    for (int i = 0; i < 4; ++i) {
        const int row = m0 + tr * 4 + i;
        if (row < M) {
            *(float4*)&C[(size_t)row * OUT_DIM + tc * 8] =
                make_float4(acc[i][0], acc[i][1], acc[i][2], acc[i][3]);
            *(float4*)&C[(size_t)row * OUT_DIM + tc * 8 + 4] =
                make_float4(acc[i][4], acc[i][5], acc[i][6], acc[i][7]);
        }
    }
}

// ---------------------------------------------------------------------------
// 6. BN stats
// ---------------------------------------------------------------------------
__global__ __launch_bounds__(256) void bn_stats(
    const float* __restrict__ agg, float* __restrict__ stats, int N)
{
    const int tid = threadIdx.x;
    const int o = tid & 127;
    const int half = tid >> 7;
    float s = 0.f, ss = 0.f;
    for (int r = blockIdx.x * 2 + half; r < N; r += gridDim.x * 2) {
        const float v = agg[(size_t)r * OUT_DIM + o];
        s += v;
        ss += v * v;
    }
    __shared__ float rs[256], rss[256];
    rs[tid] = s;
    rss[tid] = ss;
    __syncthreads();
    if (tid < 128) {
        atomicAdd(&stats[tid],       rs[tid] + rs[tid + 128]);
        atomicAdd(&stats[128 + tid], rss[tid] + rss[tid + 128]);
    }
}

// ---------------------------------------------------------------------------
// 7. finalize: BN (bias cancels), leaky_relu, residual.  In-place on d_out.
// ---------------------------------------------------------------------------
__global__ __launch_bounds__(256) void finalize(
    float* __restrict__ out, const float* __restrict__ h,
    const float* __restrict__ stats, const float* __restrict__ gamma,
    const float* __restrict__ beta, int total4, float invN)
{
    const int idx = blockIdx.x * 256 + threadIdx.x;
    if (idx >= total4) return;
    const int i4 = idx * 4;
    const int o4 = i4 & 127;

    float4 a  = *(const float4*)&out[i4];
    const float4 hh = *(const float4*)&h[i4];
    float r[4] = {a.x, a.y, a.z, a.w};
    const float hv[4] = {hh.x, hh.y, hh.z, hh.w};
    float res[4];
    #pragma unroll
    for (int j = 0; j < 4; ++j) {
        const int o = o4 + j;
        const float mean = stats[o] * invN;
        const float var = stats[128 + o] * invN - mean * mean;
        float x = (r[j] - mean) * rsqrtf(var + BN_EPS) * gamma[o] + beta[o];
        x = x > 0.f ? x : SLOPE * x;
        res[j] = x + hv[j];
    }
    *(float4*)&out[i4] = make_float4(res[0], res[1], res[2], res[3]);
}

// ---------------------------------------------------------------------------
extern "C" void kernel_launch(void* const* d_in, const int* in_sizes, int n_in,
                              void* d_out, int out_size, void* d_ws, size_t ws_size,
                              hipStream_t stream)
{
    const float* h      = (const float*)d_in[0];
    const float* pseudo = (const float*)d_in[1];
    const int*   src    = (const int*)d_in[2];
    const int*   dst    = (const int*)d_in[3];
    const float* fc_w   = (const float*)d_in[4];
    const float* mu     = (const float*)d_in[5];
    const float* isg    = (const float*)d_in[6];
    // d_in[7] = bias: cancels exactly inside BatchNorm -> unused
    const float* gamma  = (const float*)d_in[8];
    const float* beta   = (const float*)d_in[9];

    const int N = in_sizes[0] / IN_DIM;   // 50000
    const int E = in_sizes[2];            // 800000

    // workspace layout
    char* w = (char*)d_ws;
    size_t off = 0;
    float4* edata = (float4*)(w + off);  off += (size_t)E * 16;                 // 12.8 MB
    ushort* g     = (ushort*)(w + off);  off += (size_t)N * NCOL * 2;           // 38.4 MB
    off = (off + 255) & ~(size_t)255;
    int* row_start = (int*)(w + off);    off += ((size_t)N + 1) * 4;
    off = (off + 255) & ~(size_t)255;
    int* counts    = (int*)(w + off);    off += (size_t)N * 4;
    int* cursor    = (int*)(w + off);    off += (size_t)N * 4;
    float* stats   = (float*)(w + off);  off += 256 * 4;                        // counts..stats contiguous
    off = (off + 255) & ~(size_t)255;
    int* blocksum  = (int*)(w + off);    off += 128 * 4;
    int* chunk_off = (int*)(w + off);    off += 128 * 4;

    const int nch = (N + SCHUNK - 1) / SCHUNK;   // 98

    // zero counts + cursor + stats (contiguous: 2N + 256 ints)
    const int nz = 2 * N + 256;
    zero_i32<<<(nz + 255) / 256, 256, 0, stream>>>(counts, nz);

    // CSR build
    hist_dst<<<(E + 255) / 256, 256, 0, stream>>>(dst, counts, E);
    scan1<<<nch, 256, 0, stream>>>(counts, blocksum, N);
    scan2<<<1, 64, 0, stream>>>(blocksum, chunk_off, row_start, nch, N, E);
    scan3<<<nch, 512, 0, stream>>>(counts, chunk_off, row_start, N);
    edge_prep<<<(E + 255) / 256, 256, 0, stream>>>(pseudo, src, dst, mu, isg,
                                                   row_start, cursor, edata, E);

    // aggregation -> g (bf16)
    edge_aggregate<<<(N + 1) / 2, 256, 0, stream>>>(h, edata, row_start, g, N);

    // GEMM -> agg (in d_out)
    float* agg = (float*)d_out;
    gemm_agg<<<(N + TM - 1) / TM, 256, 0, stream>>>(g, fc_w, agg, N);

    // BN stats + finalize
    bn_stats<<<512, 256, 0, stream>>>(agg, stats, N);
    const int total = N * OUT_DIM;
    finalize<<<(total / 4 + 255) / 256, 256, 0, stream>>>(
        agg, h, stats, gamma, beta, total / 4, 1.0f / (float)N);
}

// Round 3
// 206.924 us; speedup vs baseline: 2.2658x; 1.4928x over previous
//
#include <hip/hip_runtime.h>

#define IN_DIM 128
#define OUT_DIM 128
#define KERN 3
#define NCOL 384          // KERN * IN_DIM
#define BN_EPS 1e-5f
#define SLOPE 0.01f

typedef unsigned int uint;
typedef unsigned short ushort;
typedef __attribute__((ext_vector_type(8))) short short8;
typedef __attribute__((ext_vector_type(4))) float f32x4;

__device__ __forceinline__ ushort f32_to_bf16(float f) {
    uint b = __float_as_uint(f);
    return (ushort)((b + 0x7fffu + ((b >> 16) & 1u)) >> 16);
}

// ---------------------------------------------------------------------------
// zero helper
// ---------------------------------------------------------------------------
__global__ void zero_i32(int* __restrict__ p, int n)
{
    const int i = blockIdx.x * 256 + threadIdx.x;
    if (i < n) p[i] = 0;
}

// ---------------------------------------------------------------------------
// h (f32) -> hb (bf16), vectorized
// ---------------------------------------------------------------------------
__global__ __launch_bounds__(256) void h2bf16(
    const float* __restrict__ h, ushort* __restrict__ hb, int total4)
{
    const int i = blockIdx.x * 256 + threadIdx.x;
    if (i >= total4) return;
    const float4 v = *(const float4*)&h[(size_t)i * 4];
    ushort4 o;
    o.x = f32_to_bf16(v.x); o.y = f32_to_bf16(v.y);
    o.z = f32_to_bf16(v.z); o.w = f32_to_bf16(v.w);
    *(ushort4*)&hb[(size_t)i * 4] = o;
}

// ---------------------------------------------------------------------------
// weight prep: Bt[o][c] = bf16(fc_w[i*384 + k*128 + o]), c = k*128+i
// ---------------------------------------------------------------------------
__global__ __launch_bounds__(256) void wprep(
    const float* __restrict__ W, ushort* __restrict__ Bt)
{
    const int idx = blockIdx.x * 256 + threadIdx.x;   // 128*384 total
    if (idx >= 128 * NCOL) return;
    const int o = idx / NCOL;
    const int c = idx - o * NCOL;
    const int i = c & 127;
    const int k = c >> 7;
    Bt[idx] = f32_to_bf16(W[(size_t)i * NCOL + (k << 7) + o]);
}

// ---------------------------------------------------------------------------
// 1. histogram of dst
// ---------------------------------------------------------------------------
__global__ __launch_bounds__(256) void hist_dst(
    const int* __restrict__ dst, int* __restrict__ counts, int E)
{
    const int e = blockIdx.x * 256 + threadIdx.x;
    if (e < E) atomicAdd(&counts[dst[e]], 1);
}

// ---------------------------------------------------------------------------
// 2. prefix sum of counts -> row_start
// ---------------------------------------------------------------------------
#define SCHUNK 512

__global__ __launch_bounds__(256) void scan1(
    const int* __restrict__ counts, int* __restrict__ blocksum, int N)
{
    __shared__ int s[256];
    const int tid = threadIdx.x;
    const int base = blockIdx.x * SCHUNK;
    int v = 0;
    if (base + tid < N) v += counts[base + tid];
    if (base + 256 + tid < N) v += counts[base + 256 + tid];
    s[tid] = v;
    __syncthreads();
    for (int off = 128; off > 0; off >>= 1) {
        if (tid < off) s[tid] += s[tid + off];
        __syncthreads();
    }
    if (tid == 0) blocksum[blockIdx.x] = s[0];
}

__global__ void scan2(const int* __restrict__ blocksum,
                      int* __restrict__ chunk_off,
                      int* __restrict__ row_start, int nch, int N, int E)
{
    if (threadIdx.x == 0) {
        int run = 0;
        for (int b = 0; b < nch; ++b) { chunk_off[b] = run; run += blocksum[b]; }
        row_start[N] = E;
    }
}

__global__ __launch_bounds__(512) void scan3(
    const int* __restrict__ counts, const int* __restrict__ chunk_off,
    int* __restrict__ row_start, int N)
{
    __shared__ int s[SCHUNK];
    const int tid = threadIdx.x;
    const int i = blockIdx.x * SCHUNK + tid;
    const int v0 = (i < N) ? counts[i] : 0;
    s[tid] = v0;
    __syncthreads();
    for (int off = 1; off < SCHUNK; off <<= 1) {
        int t = 0;
        if (tid >= off) t = s[tid - off];
        __syncthreads();
        s[tid] += t;
        __syncthreads();
    }
    if (i < N) row_start[i] = chunk_off[blockIdx.x] + s[tid] - v0;
}

// ---------------------------------------------------------------------------
// 3. per-edge: gaussian weights + scatter {w0,w1,w2,src} into dst-sorted slot
// ---------------------------------------------------------------------------
__global__ __launch_bounds__(256) void edge_prep(
    const float* __restrict__ pseudo, const int* __restrict__ src,
    const int* __restrict__ dst, const float* __restrict__ mu,
    const float* __restrict__ isg, const int* __restrict__ row_start,
    int* __restrict__ cursor, float4* __restrict__ edata, int E)
{
    const int e = blockIdx.x * 256 + threadIdx.x;
    if (e >= E) return;
    const float2 p = *(const float2*)&pseudo[(size_t)e * 2];
    float w[KERN];
    #pragma unroll
    for (int k = 0; k < KERN; ++k) {
        const float dx = (p.x - mu[2 * k])     * isg[2 * k];
        const float dy = (p.y - mu[2 * k + 1]) * isg[2 * k + 1];
        w[k] = __expf(-0.5f * (dx * dx + dy * dy));
    }
    const int d = dst[e];
    const int pos = row_start[d] + atomicAdd(&cursor[d], 1);
    edata[pos] = make_float4(w[0], w[1], w[2], __int_as_float(src[e]));
}

// ---------------------------------------------------------------------------
// 4. aggregation: g[d, k*128+i] = sum_{e->d} w_ek * hb[src_e, i]  (bf16 io)
//    64 threads per node (ushort2 per thread), 4 nodes per block.
// ---------------------------------------------------------------------------
__global__ __launch_bounds__(256) void edge_aggregate(
    const ushort* __restrict__ hb, const float4* __restrict__ edata,
    const int* __restrict__ row_start, ushort* __restrict__ g, int N)
{
    const int d = blockIdx.x * 4 + (threadIdx.x >> 6);
    const int o2 = (threadIdx.x & 63) * 2;
    if (d >= N) return;

    const int beg = row_start[d];
    const int end = row_start[d + 1];
    float a00 = 0.f, a01 = 0.f, a10 = 0.f, a11 = 0.f, a20 = 0.f, a21 = 0.f;

    int i = beg;
    for (; i + 1 < end; i += 2) {
        const float4 e0 = edata[i];
        const float4 e1 = edata[i + 1];
        const uint u0 = *(const uint*)&hb[(size_t)__float_as_int(e0.w) * IN_DIM + o2];
        const uint u1 = *(const uint*)&hb[(size_t)__float_as_int(e1.w) * IN_DIM + o2];
        const float v00 = __uint_as_float(u0 << 16);
        const float v01 = __uint_as_float(u0 & 0xffff0000u);
        const float v10 = __uint_as_float(u1 << 16);
        const float v11 = __uint_as_float(u1 & 0xffff0000u);
        a00 += e0.x * v00; a01 += e0.x * v01;
        a10 += e0.y * v00; a11 += e0.y * v01;
        a20 += e0.z * v00; a21 += e0.z * v01;
        a00 += e1.x * v10; a01 += e1.x * v11;
        a10 += e1.y * v10; a11 += e1.y * v11;
        a20 += e1.z * v10; a21 += e1.z * v11;
    }
    if (i < end) {
        const float4 e0 = edata[i];
        const uint u0 = *(const uint*)&hb[(size_t)__float_as_int(e0.w) * IN_DIM + o2];
        const float v00 = __uint_as_float(u0 << 16);
        const float v01 = __uint_as_float(u0 & 0xffff0000u);
        a00 += e0.x * v00; a01 += e0.x * v01;
        a10 += e0.y * v00; a11 += e0.y * v01;
        a20 += e0.z * v00; a21 += e0.z * v01;
    }

    ushort* gp = g + (size_t)d * NCOL + o2;
    *(uint*)&gp[0]           = (uint)f32_to_bf16(a00) | ((uint)f32_to_bf16(a01) << 16);
    *(uint*)&gp[IN_DIM]      = (uint)f32_to_bf16(a10) | ((uint)f32_to_bf16(a11) << 16);
    *(uint*)&gp[2 * IN_DIM]  = (uint)f32_to_bf16(a20) | ((uint)f32_to_bf16(a21) << 16);
}

// ---------------------------------------------------------------------------
// 5. MFMA GEMM: C[M,128] = g[M,384] @ B, Bt[o][c] pre-permuted/transposed.
//    128x128 tile, BK=64, 4 waves (2x2), 16x16x32 bf16 MFMA.
//    XOR-swizzled LDS (T2).  Fused per-channel BN stats.
// ---------------------------------------------------------------------------
#define BM 128
#define BK 64

__global__ __launch_bounds__(256) void gemm_mfma(
    const ushort* __restrict__ A, const ushort* __restrict__ Bt,
    float* __restrict__ C, float* __restrict__ stats, int M)
{
    __shared__ ushort As[BM * BK];   // row r at bytes [r*128, r*128+128), swizzled
    __shared__ ushort Bs[128 * BK];
    __shared__ float sred[256];

    const int tid = threadIdx.x;
    const int lane = tid & 63;
    const int wid = tid >> 6;
    const int wm = wid >> 1;          // 0..1 -> rows wm*64..
    const int wn = wid & 1;           // 0..1 -> cols wn*64..
    const int m0 = blockIdx.x * BM;

    f32x4 acc[4][4] = {};

    const int lrow = lane & 15;
    const int lk16 = (lane >> 4) * 16;   // byte offset of this lane's 8 bf16

    for (int k0 = 0; k0 < NCOL; k0 += BK) {
        #pragma unroll
        for (int p = 0; p < 4; ++p) {
            const int r = (tid >> 3) + p * 32;
            const int s = tid & 7;
            int grow = m0 + r; if (grow >= M) grow = M - 1;
            const uint4 v = *(const uint4*)&A[(size_t)grow * NCOL + k0 + s * 8];
            *(uint4*)((char*)As + r * 128 + ((s * 16) ^ ((r & 7) << 4))) = v;
        }
        #pragma unroll
        for (int p = 0; p < 4; ++p) {
            const int r = (tid >> 3) + p * 32;
            const int s = tid & 7;
            const uint4 v = *(const uint4*)&Bt[(size_t)r * NCOL + k0 + s * 8];
            *(uint4*)((char*)Bs + r * 128 + ((s * 16) ^ ((r & 7) << 4))) = v;
        }
        __syncthreads();

        #pragma unroll
        for (int kk = 0; kk < 2; ++kk) {
            short8 af[4], bfr[4];
            #pragma unroll
            for (int i = 0; i < 4; ++i) {
                const int r = wm * 64 + i * 16 + lrow;
                af[i] = *(const short8*)((const char*)As +
                        r * 128 + ((kk * 64 + lk16) ^ ((r & 7) << 4)));
                const int n = wn * 64 + i * 16 + lrow;
                bfr[i] = *(const short8*)((const char*)Bs +
                        n * 128 + ((kk * 64 + lk16) ^ ((n & 7) << 4)));
            }
            #pragma unroll
            for (int i = 0; i < 4; ++i)
                #pragma unroll
                for (int j = 0; j < 4; ++j)
                    acc[i][j] = __builtin_amdgcn_mfma_f32_16x16x32_bf16(
                        af[i], bfr[j], acc[i][j], 0, 0, 0);
        }
        __syncthreads();
    }

    // epilogue: write C + per-channel sums/sumsq
    float s[4] = {0.f, 0.f, 0.f, 0.f};
    float ss[4] = {0.f, 0.f, 0.f, 0.f};
    const int rbase = m0 + wm * 64 + (lane >> 4) * 4;
    #pragma unroll
    for (int i = 0; i < 4; ++i) {
        #pragma unroll
        for (int r = 0; r < 4; ++r) {
            const int row = rbase + i * 16 + r;
            if (row < M) {
                #pragma unroll
                for (int j = 0; j < 4; ++j) {
                    const float v = acc[i][j][r];
                    C[(size_t)row * OUT_DIM + wn * 64 + j * 16 + lrow] = v;
                    s[j] += v;
                    ss[j] += v * v;
                }
            }
        }
    }
    sred[tid] = 0.f;
    __syncthreads();
    #pragma unroll
    for (int j = 0; j < 4; ++j) {
        const int col = wn * 64 + j * 16 + lrow;
        atomicAdd(&sred[col], s[j]);
        atomicAdd(&sred[128 + col], ss[j]);
    }
    __syncthreads();
    if (tid < 256) atomicAdd(&stats[tid], sred[tid]);
}

// ---------------------------------------------------------------------------
// 6. finalize: BN (bias cancels), leaky_relu, residual.  In-place on d_out.
// ---------------------------------------------------------------------------
__global__ __launch_bounds__(256) void finalize(
    float* __restrict__ out, const float* __restrict__ h,
    const float* __restrict__ stats, const float* __restrict__ gamma,
    const float* __restrict__ beta, int total4, float invN)
{
    const int idx = blockIdx.x * 256 + threadIdx.x;
    if (idx >= total4) return;
    const int i4 = idx * 4;
    const int o4 = i4 & 127;

    float4 a  = *(const float4*)&out[i4];
    const float4 hh = *(const float4*)&h[i4];
    float r[4] = {a.x, a.y, a.z, a.w};
    const float hv[4] = {hh.x, hh.y, hh.z, hh.w};
    float res[4];
    #pragma unroll
    for (int j = 0; j < 4; ++j) {
        const int o = o4 + j;
        const float mean = stats[o] * invN;
        const float var = stats[128 + o] * invN - mean * mean;
        float x = (r[j] - mean) * rsqrtf(var + BN_EPS) * gamma[o] + beta[o];
        x = x > 0.f ? x : SLOPE * x;
        res[j] = x + hv[j];
    }
    *(float4*)&out[i4] = make_float4(res[0], res[1], res[2], res[3]);
}

// ---------------------------------------------------------------------------
extern "C" void kernel_launch(void* const* d_in, const int* in_sizes, int n_in,
                              void* d_out, int out_size, void* d_ws, size_t ws_size,
                              hipStream_t stream)
{
    const float* h      = (const float*)d_in[0];
    const float* pseudo = (const float*)d_in[1];
    const int*   src    = (const int*)d_in[2];
    const int*   dst    = (const int*)d_in[3];
    const float* fc_w   = (const float*)d_in[4];
    const float* mu     = (const float*)d_in[5];
    const float* isg    = (const float*)d_in[6];
    // d_in[7] = bias: cancels exactly inside BatchNorm -> unused
    const float* gamma  = (const float*)d_in[8];
    const float* beta   = (const float*)d_in[9];

    const int N = in_sizes[0] / IN_DIM;   // 50000
    const int E = in_sizes[2];            // 800000

    // workspace layout
    char* w = (char*)d_ws;
    size_t off = 0;
    float4* edata = (float4*)(w + off);  off += (size_t)E * 16;                 // 12.8 MB
    ushort* g     = (ushort*)(w + off);  off += (size_t)N * NCOL * 2;           // 38.4 MB
    ushort* hb    = (ushort*)(w + off);  off += (size_t)N * IN_DIM * 2;         // 12.8 MB
    ushort* Bt    = (ushort*)(w + off);  off += (size_t)128 * NCOL * 2;         // 96 KB
    off = (off + 255) & ~(size_t)255;
    int* row_start = (int*)(w + off);    off += ((size_t)N + 1) * 4;
    off = (off + 255) & ~(size_t)255;
    int* counts    = (int*)(w + off);    off += (size_t)N * 4;
    int* cursor    = (int*)(w + off);    off += (size_t)N * 4;
    float* stats   = (float*)(w + off);  off += 256 * 4;    // counts..stats contiguous
    off = (off + 255) & ~(size_t)255;
    int* blocksum  = (int*)(w + off);    off += 128 * 4;
    int* chunk_off = (int*)(w + off);    off += 128 * 4;

    const int nch = (N + SCHUNK - 1) / SCHUNK;   // 98

    // zero counts + cursor + stats (contiguous: 2N + 256 ints)
    const int nz = 2 * N + 256;
    zero_i32<<<(nz + 255) / 256, 256, 0, stream>>>(counts, nz);

    // precision prep
    h2bf16<<<(N * IN_DIM / 4 + 255) / 256, 256, 0, stream>>>(h, hb, N * IN_DIM / 4);
    wprep<<<(128 * NCOL + 255) / 256, 256, 0, stream>>>(fc_w, Bt);

    // CSR build
    hist_dst<<<(E + 255) / 256, 256, 0, stream>>>(dst, counts, E);
    scan1<<<nch, 256, 0, stream>>>(counts, blocksum, N);
    scan2<<<1, 64, 0, stream>>>(blocksum, chunk_off, row_start, nch, N, E);
    scan3<<<nch, 512, 0, stream>>>(counts, chunk_off, row_start, N);
    edge_prep<<<(E + 255) / 256, 256, 0, stream>>>(pseudo, src, dst, mu, isg,
                                                   row_start, cursor, edata, E);

    // aggregation -> g (bf16)
    edge_aggregate<<<(N + 3) / 4, 256, 0, stream>>>(hb, edata, row_start, g, N);

    // MFMA GEMM -> agg (in d_out), fused BN stats
    float* agg = (float*)d_out;
    gemm_mfma<<<(N + BM - 1) / BM, 256, 0, stream>>>(g, Bt, agg, stats, N);

    // BN + leaky_relu + residual
    const int total = N * OUT_DIM;
    finalize<<<(total / 4 + 255) / 256, 256, 0, stream>>>(
        agg, h, stats, gamma, beta, total / 4, 1.0f / (float)N);
}